// Round 2
// baseline (790.759 us; speedup 1.0000x reference)
//
#include <hip/hip_runtime.h>
#include <hip/hip_bf16.h>

// Problem constants
namespace {
constexpr int kHW   = 40;              // spatial side
constexpr int kNPIX = kHW * kHW;       // 1600
constexpr int kDIM  = 256;
constexpr int kPADW = 42;              // padded side
constexpr int kPPIX = kPADW * kPADW;   // 1764
constexpr int kACOL = 648;             // heads * 9 * 9
constexpr float kSCALE = 0.17677669529663687f;  // 32^-0.5
}

// ---------------------------------------------------------------------------
// Zero-pad CHW [256][40][40] -> [256][42][42]
__global__ __launch_bounds__(256) void pad42(const float* __restrict__ in,
                                             float* __restrict__ out) {
  int idx = blockIdx.x * 256 + threadIdx.x;           // 256*1764 total
  if (idx >= kDIM * kPPIX) return;
  int c = idx / kPPIX;
  int r = idx % kPPIX;
  int py = r / kPADW, px = r % kPADW;
  float v = 0.f;
  if (py >= 1 && py <= kHW && px >= 1 && px <= kHW)
    v = in[c * kNPIX + (py - 1) * kHW + (px - 1)];
  out[idx] = v;
}

// ---------------------------------------------------------------------------
// 3x3 conv (padded input) + per-channel scale/shift + ReLU.
// Block: 256 threads = 256-pixel tile; 4 output channels per block.
// Weight reads are wave-uniform -> scalar loads.
__global__ __launch_bounds__(256) void conv3_cbr(const float* __restrict__ pin,
                                                 const float* __restrict__ W,
                                                 const float* __restrict__ sc,
                                                 const float* __restrict__ sh,
                                                 float* __restrict__ out) {
  constexpr int OCP = 4;
  int ob = (blockIdx.x / 7) * OCP;
  int l  = (blockIdx.x % 7) * 256 + threadIdx.x;
  if (l >= kNPIX) return;
  int y = l / kHW, x = l % kHW;
  const float* ip0 = pin + (y + 1) * kPADW + (x + 1);

  float acc0 = 0.f, acc1 = 0.f, acc2 = 0.f, acc3 = 0.f;
  const float* wb = W + (size_t)ob * kDIM * 9;

#pragma unroll 2
  for (int i = 0; i < kDIM; ++i) {
    const float* ip = ip0 + i * kPPIX;
    float v0 = ip[-kPADW - 1], v1 = ip[-kPADW], v2 = ip[-kPADW + 1];
    float v3 = ip[-1],         v4 = ip[0],      v5 = ip[1];
    float v6 = ip[kPADW - 1],  v7 = ip[kPADW],  v8 = ip[kPADW + 1];
    const float* w0 = wb + i * 9;
#pragma unroll
    for (int o = 0; o < OCP; ++o) {
      const float* w = w0 + o * kDIM * 9;
      float a = (o == 0) ? acc0 : (o == 1) ? acc1 : (o == 2) ? acc2 : acc3;
      a = fmaf(w[0], v0, a); a = fmaf(w[1], v1, a); a = fmaf(w[2], v2, a);
      a = fmaf(w[3], v3, a); a = fmaf(w[4], v4, a); a = fmaf(w[5], v5, a);
      a = fmaf(w[6], v6, a); a = fmaf(w[7], v7, a); a = fmaf(w[8], v8, a);
      if (o == 0) acc0 = a; else if (o == 1) acc1 = a; else if (o == 2) acc2 = a; else acc3 = a;
    }
  }

#pragma unroll
  for (int o = 0; o < OCP; ++o) {
    float a = (o == 0) ? acc0 : (o == 1) ? acc1 : (o == 2) ? acc2 : acc3;
    float r = fmaxf(fmaf(a, sc[ob + o], sh[ob + o]), 0.f);
    out[(ob + o) * kNPIX + l] = r;
  }
}

// ---------------------------------------------------------------------------
// v = h0(BHWC) @ Wv + bv, written HWC.  Block per pixel; h0 read is uniform.
__global__ __launch_bounds__(256) void linear_v(const float* __restrict__ h0,
                                                const float* __restrict__ Wv,
                                                const float* __restrict__ bv,
                                                float* __restrict__ v_hwc) {
  int l = blockIdx.x;
  int t = threadIdx.x;
  float acc = bv[t];
  for (int c = 0; c < kDIM; ++c)
    acc = fmaf(h0[c * kNPIX + l], Wv[c * kDIM + t], acc);
  v_hwc[l * kDIM + t] = acc;
}

// ---------------------------------------------------------------------------
// Tiled 32x32 transpose: in R x C  ->  out C x R.
__global__ __launch_bounds__(256) void transpose_k(const float* __restrict__ in,
                                                   float* __restrict__ out,
                                                   int R, int C) {
  __shared__ float tile[32][33];
  int nbx = C / 32;
  int bx = blockIdx.x % nbx, by = blockIdx.x / nbx;
  int c0 = bx * 32, r0 = by * 32;
  int tx = threadIdx.x % 32, ty = threadIdx.x / 32;  // 32x8
#pragma unroll
  for (int rr = ty; rr < 32; rr += 8)
    tile[rr][tx] = in[(r0 + rr) * C + c0 + tx];
  __syncthreads();
#pragma unroll
  for (int rr = ty; rr < 32; rr += 8)
    out[(c0 + rr) * R + r0 + tx] = tile[tx][rr];
}

// ---------------------------------------------------------------------------
// Per-pixel attention: logits GEMV -> softmax(9) -> xw = attn @ vu.
// xw written as [l][p][c] (coalesced across c).
__global__ __launch_bounds__(256) void attn_kernel(const float* __restrict__ feat_hwc,
                                                   const float* __restrict__ v_hwc,
                                                   const float* __restrict__ Wa,
                                                   const float* __restrict__ ba,
                                                   float* __restrict__ xw) {
  __shared__ float feat[kDIM];
  __shared__ float vu[9][kDIM];
  __shared__ float att[kACOL];

  int l = blockIdx.x;
  int y = l / kHW, x = l % kHW;
  int t = threadIdx.x;

  feat[t] = feat_hwc[l * kDIM + t];
#pragma unroll
  for (int q = 0; q < 9; ++q) {
    int qy = y + q / 3 - 1;
    int qx = x + q % 3 - 1;
    bool ok = (qy >= 0 && qy < kHW && qx >= 0 && qx < kHW);
    vu[q][t] = ok ? v_hwc[(qy * kHW + qx) * kDIM + t] : 0.f;
  }
  __syncthreads();

  // logits (pre-softmax), a = head*81 + p*9 + q
#pragma unroll
  for (int r = 0; r < 3; ++r) {
    int a = t + r * 256;
    if (a < kACOL) {
      float acc = ba[a];
      for (int c = 0; c < kDIM; ++c)
        acc = fmaf(feat[c], Wa[c * kACOL + a], acc);
      att[a] = acc * kSCALE;
    }
  }
  __syncthreads();

  // softmax over q for each of the 72 (head, p) groups
  if (t < 72) {
    float* g = &att[t * 9];
    float m = g[0];
#pragma unroll
    for (int q = 1; q < 9; ++q) m = fmaxf(m, g[q]);
    float e[9], s = 0.f;
#pragma unroll
    for (int q = 0; q < 9; ++q) { e[q] = __expf(g[q] - m); s += e[q]; }
    float inv = 1.f / s;
#pragma unroll
    for (int q = 0; q < 9; ++q) g[q] = e[q] * inv;
  }
  __syncthreads();

  // xw[n,l,p,d] ; thread t = channel c = n*32+d
  int n = t >> 5;
  const float* an = &att[n * 81];
#pragma unroll
  for (int p = 0; p < 9; ++p) {
    float acc = 0.f;
#pragma unroll
    for (int q = 0; q < 9; ++q)
      acc = fmaf(an[p * 9 + q], vu[q][t], acc);
    xw[(l * 9 + p) * kDIM + t] = acc;
  }
}

// ---------------------------------------------------------------------------
// fold (overlap-add gather, deterministic) + projection @ Wp + bp. Output HWC.
__global__ __launch_bounds__(256) void fold_proj(const float* __restrict__ xw,
                                                 const float* __restrict__ Wp,
                                                 const float* __restrict__ bp,
                                                 float* __restrict__ out_hwc) {
  __shared__ float folded[kDIM];
  int l = blockIdx.x;
  int Y = l / kHW, X = l % kHW;
  int t = threadIdx.x;

  float acc = 0.f;
#pragma unroll
  for (int i = 0; i < 3; ++i) {
    int ys = Y + 1 - i;
    if (ys < 0 || ys >= kHW) continue;
#pragma unroll
    for (int j = 0; j < 3; ++j) {
      int xs = X + 1 - j;
      if (xs < 0 || xs >= kHW) continue;
      int ls = ys * kHW + xs;
      int p = i * 3 + j;
      acc += xw[(ls * 9 + p) * kDIM + t];
    }
  }
  folded[t] = acc;
  __syncthreads();

  float o = bp[t];
  for (int c = 0; c < kDIM; ++c)
    o = fmaf(folded[c], Wp[c * kDIM + t], o);
  out_hwc[l * kDIM + t] = o;
}

// ---------------------------------------------------------------------------
extern "C" void kernel_launch(void* const* d_in, const int* in_sizes, int n_in,
                              void* d_out, int out_size, void* d_ws, size_t ws_size,
                              hipStream_t stream) {
  const float* x   = (const float*)d_in[0];
  const float* fg  = (const float*)d_in[1];
  const float* bg  = (const float*)d_in[2];
  const float* Wc1 = (const float*)d_in[3];
  const float* s1  = (const float*)d_in[4];
  const float* b1  = (const float*)d_in[5];
  const float* Wc2 = (const float*)d_in[6];
  const float* s2  = (const float*)d_in[7];
  const float* b2  = (const float*)d_in[8];
  const float* Wv  = (const float*)d_in[9];
  const float* bv  = (const float*)d_in[10];
  const float* Wfg = (const float*)d_in[11];
  const float* bfg = (const float*)d_in[12];
  const float* Wbg = (const float*)d_in[13];
  const float* bbg = (const float*)d_in[14];
  const float* Wp  = (const float*)d_in[15];
  const float* bp  = (const float*)d_in[16];
  const float* Wc3 = (const float*)d_in[17];
  const float* s3  = (const float*)d_in[18];
  const float* b3  = (const float*)d_in[19];
  const float* Wc4 = (const float*)d_in[20];
  const float* s4  = (const float*)d_in[21];
  const float* b4  = (const float*)d_in[22];
  float* out = (float*)d_out;   // reference output dtype is float32 (NCHW)

  float* ws = (float*)d_ws;
  float* A0 = ws;                         // 409600
  float* A1 = ws + 409600;                // 409600
  float* A2 = ws + 819200;                // 409600
  float* A3 = ws + 1228800;               // 409600
  float* XW = ws + 1638400;               // 3686400
  float* P  = ws + 5324800;               // 451584  (total 23.1 MB)

  const int padGrid  = (kDIM * kPPIX + 255) / 256;  // 1764
  const int convGrid = (kDIM / 4) * 7;              // 448
  const int tpGrid   = (kNPIX / 32) * (kDIM / 32);  // 400

  // input_cbr
  pad42<<<padGrid, 256, 0, stream>>>(x, P);
  conv3_cbr<<<convGrid, 256, 0, stream>>>(P, Wc1, s1, b1, A0);
  pad42<<<padGrid, 256, 0, stream>>>(A0, P);
  conv3_cbr<<<convGrid, 256, 0, stream>>>(P, Wc2, s2, b2, A1);

  // v projection (HWC)
  linear_v<<<kNPIX, 256, 0, stream>>>(A1, Wv, bv, A2);

  // fg attention pass
  transpose_k<<<tpGrid, 256, 0, stream>>>(fg, A0, kDIM, kNPIX);   // fg -> HWC
  attn_kernel<<<kNPIX, 256, 0, stream>>>(A0, A2, Wfg, bfg, XW);
  fold_proj<<<kNPIX, 256, 0, stream>>>(XW, Wp, bp, A3);           // x1 HWC

  // bg attention pass (v = x1)
  transpose_k<<<tpGrid, 256, 0, stream>>>(bg, A0, kDIM, kNPIX);   // bg -> HWC
  attn_kernel<<<kNPIX, 256, 0, stream>>>(A0, A3, Wbg, bbg, XW);
  fold_proj<<<kNPIX, 256, 0, stream>>>(XW, Wp, bp, A1);           // x2 HWC

  // output_cbr
  transpose_k<<<tpGrid, 256, 0, stream>>>(A1, A2, kNPIX, kDIM);   // x2 -> CHW
  pad42<<<padGrid, 256, 0, stream>>>(A2, P);
  conv3_cbr<<<convGrid, 256, 0, stream>>>(P, Wc3, s3, b3, A3);
  pad42<<<padGrid, 256, 0, stream>>>(A3, P);
  conv3_cbr<<<convGrid, 256, 0, stream>>>(P, Wc4, s4, b4, out);
}

// Round 3
// 267.675 us; speedup vs baseline: 2.9542x; 2.9542x over previous
//
#include <hip/hip_runtime.h>
#include <hip/hip_bf16.h>

namespace {
constexpr int kHW   = 40;
constexpr int kNPIX = kHW * kHW;        // 1600
constexpr int kDIM  = 256;
constexpr int kPADW = 42;
constexpr int kACOL = 648;              // heads * 9 * 9
constexpr float kSCALE = 0.17677669529663687f;  // 32^-0.5
}

using bf16 = __hip_bfloat16;
typedef __attribute__((ext_vector_type(8))) short sh8;    // 8 bf16 (A/B frag)
typedef __attribute__((ext_vector_type(4))) float f32x4;  // C/D frag

static __device__ __forceinline__ bf16 f2bf(float f)  { return __float2bfloat16(f); }
static __device__ __forceinline__ float bf2f(bf16 b)  { return __bfloat162float(b); }

// ---------------------------------------------------------------------------
// Weight transform: W[oc][ic][3][3] f32 -> Wt[t][oc][ic] bf16   (589824 elems)
__global__ __launch_bounds__(256) void prep_w(const float* __restrict__ W,
                                              bf16* __restrict__ Wt) {
  int i = blockIdx.x * 256 + threadIdx.x;
  int ic = i & 255, oc = (i >> 8) & 255, t = i >> 16;
  Wt[i] = f2bf(W[(oc * 256 + ic) * 9 + t]);
}

// CHW f32 -> padded HWC bf16 (interior only; borders pre-zeroed)
__global__ __launch_bounds__(256) void prep_chw(const float* __restrict__ in,
                                                bf16* __restrict__ outb) {
  int l = blockIdx.x, c = threadIdx.x;
  int y = l / kHW, x = l % kHW;
  outb[((y + 1) * kPADW + x + 1) * kDIM + c] = f2bf(in[c * kNPIX + l]);
}

// HWC f32 -> padded HWC bf16
__global__ __launch_bounds__(256) void prep_hwc(const float* __restrict__ in,
                                                bf16* __restrict__ outb) {
  int l = blockIdx.x, c = threadIdx.x;
  int y = l / kHW, x = l % kHW;
  outb[((y + 1) * kPADW + x + 1) * kDIM + c] = f2bf(in[l * kDIM + c]);
}

// ---------------------------------------------------------------------------
// MFMA implicit-GEMM 3x3 conv + scale/shift + ReLU.
// act: padded HWC bf16 [42][42][256]; wt: [9][256][256] (tap, oc, ic) bf16.
// Block: 4 waves; tile 32 pix (4x8) x 32 oc; waves split K by ic-quarters,
// LDS reduction at the end. Grid: (50 pixel tiles, 8 oc tiles).
__global__ __launch_bounds__(256) void conv_mfma(const bf16* __restrict__ act,
                                                 const bf16* __restrict__ wt,
                                                 const float* __restrict__ sc,
                                                 const float* __restrict__ sh_,
                                                 bf16* __restrict__ outPad,
                                                 float* __restrict__ outF32) {
  int pt  = blockIdx.x;
  int oc0 = blockIdx.y * 32;
  int ty0 = (pt / 5) * 4;          // pixel-tile y base (0..36)
  int tx0 = (pt % 5) * 8;          // pixel-tile x base (0..32)
  int tid = threadIdx.x;
  int w    = tid >> 6;
  int lane = tid & 63;
  int g    = lane >> 4;            // k-group 0..3
  int r16  = lane & 15;

  // A-frag pixel coords: frag mi pixels p = mi*16 + r16 -> dy=p>>3, dx=p&7
  int dy0 = r16 >> 3,      dx0 = r16 & 7;
  int dy1 = 2 + (r16 >> 3), dx1 = r16 & 7;

  f32x4 acc[2][2] = {};
  int icq = w * 64;                // this wave's ic quarter

  for (int t = 0; t < 9; ++t) {
    int tyy = t / 3, txx = t % 3;
    const bf16* aBase0 = act + (size_t)((ty0 + dy0 + tyy) * kPADW + tx0 + dx0 + txx) * kDIM;
    const bf16* aBase1 = act + (size_t)((ty0 + dy1 + tyy) * kPADW + tx0 + dx1 + txx) * kDIM;
    const bf16* bBase  = wt + (size_t)(t * 256 + oc0 + r16) * 256;
#pragma unroll
    for (int kk = 0; kk < 2; ++kk) {
      int ic = icq + kk * 32 + g * 8;
      sh8 a0 = *(const sh8*)(aBase0 + ic);
      sh8 a1 = *(const sh8*)(aBase1 + ic);
      sh8 b0 = *(const sh8*)(bBase + ic);
      sh8 b1 = *(const sh8*)(bBase + 16 * 256 + ic);
      acc[0][0] = __builtin_amdgcn_mfma_f32_16x16x32_bf16(a0, b0, acc[0][0], 0, 0, 0);
      acc[0][1] = __builtin_amdgcn_mfma_f32_16x16x32_bf16(a0, b1, acc[0][1], 0, 0, 0);
      acc[1][0] = __builtin_amdgcn_mfma_f32_16x16x32_bf16(a1, b0, acc[1][0], 0, 0, 0);
      acc[1][1] = __builtin_amdgcn_mfma_f32_16x16x32_bf16(a1, b1, acc[1][1], 0, 0, 0);
    }
  }

  // cross-wave K reduction in LDS. D layout: row(pix)=g*4+q, col(oc)=r16.
  __shared__ float red[4][32][33];
#pragma unroll
  for (int mi = 0; mi < 2; ++mi)
#pragma unroll
    for (int ni = 0; ni < 2; ++ni)
#pragma unroll
      for (int q = 0; q < 4; ++q)
        red[w][mi * 16 + g * 4 + q][ni * 16 + r16] = acc[mi][ni][q];
  __syncthreads();

  // 1024 outputs; thread -> 4 consecutive oc at one pixel
  int pixL = tid >> 3;
  int ocL  = (tid & 7) * 4;
  int dy = pixL >> 3, dx = pixL & 7;
  int oc = oc0 + ocL;
  int y = ty0 + dy, x = tx0 + dx;
  float v[4];
#pragma unroll
  for (int j = 0; j < 4; ++j) {
    float s = red[0][pixL][ocL + j] + red[1][pixL][ocL + j] +
              red[2][pixL][ocL + j] + red[3][pixL][ocL + j];
    v[j] = fmaxf(fmaf(s, sc[oc + j], sh_[oc + j]), 0.f);
  }
  if (outPad) {
    bf16 pk[4];
#pragma unroll
    for (int j = 0; j < 4; ++j) pk[j] = f2bf(v[j]);
    *reinterpret_cast<uint2*>(outPad + (size_t)((y + 1) * kPADW + x + 1) * kDIM + oc) =
        *reinterpret_cast<uint2*>(pk);
  } else {
#pragma unroll
    for (int j = 0; j < 4; ++j)
      outF32[(oc + j) * kNPIX + y * kHW + x] = v[j];
  }
}

// ---------------------------------------------------------------------------
// v = h0 @ Wv + bv from padded bf16 HWC; writes f32 HWC.
__global__ __launch_bounds__(256) void linear_v_pad(const bf16* __restrict__ h0b,
                                                    const float* __restrict__ Wv,
                                                    const float* __restrict__ bv,
                                                    float* __restrict__ v_hwc) {
  int l = blockIdx.x, t = threadIdx.x;
  int y = l / kHW, x = l % kHW;
  const bf16* hp = h0b + (size_t)((y + 1) * kPADW + x + 1) * kDIM;
  float acc = bv[t];
  for (int c = 0; c < kDIM; ++c)
    acc = fmaf(bf2f(hp[c]), Wv[c * kDIM + t], acc);
  v_hwc[l * kDIM + t] = acc;
}

// ---------------------------------------------------------------------------
// Tiled 32x32 transpose: in R x C -> out C x R (f32).
__global__ __launch_bounds__(256) void transpose_k(const float* __restrict__ in,
                                                   float* __restrict__ out,
                                                   int R, int C) {
  __shared__ float tile[32][33];
  int nbx = C / 32;
  int bx = blockIdx.x % nbx, by = blockIdx.x / nbx;
  int c0 = bx * 32, r0 = by * 32;
  int tx = threadIdx.x % 32, ty = threadIdx.x / 32;
#pragma unroll
  for (int rr = ty; rr < 32; rr += 8)
    tile[rr][tx] = in[(r0 + rr) * C + c0 + tx];
  __syncthreads();
#pragma unroll
  for (int rr = ty; rr < 32; rr += 8)
    out[(c0 + rr) * R + r0 + tx] = tile[tx][rr];
}

// ---------------------------------------------------------------------------
// Per-pixel attention: logits GEMV -> softmax(9) -> xw = attn @ vu (bf16 out).
__global__ __launch_bounds__(256) void attn_kernel(const float* __restrict__ feat_hwc,
                                                   const float* __restrict__ v_hwc,
                                                   const float* __restrict__ Wa,
                                                   const float* __restrict__ ba,
                                                   bf16* __restrict__ xw) {
  __shared__ float feat[kDIM];
  __shared__ float vu[9][kDIM];
  __shared__ float att[kACOL];

  int l = blockIdx.x;
  int y = l / kHW, x = l % kHW;
  int t = threadIdx.x;

  feat[t] = feat_hwc[l * kDIM + t];
#pragma unroll
  for (int q = 0; q < 9; ++q) {
    int qy = y + q / 3 - 1;
    int qx = x + q % 3 - 1;
    bool ok = (qy >= 0 && qy < kHW && qx >= 0 && qx < kHW);
    vu[q][t] = ok ? v_hwc[(qy * kHW + qx) * kDIM + t] : 0.f;
  }
  __syncthreads();

#pragma unroll
  for (int r = 0; r < 3; ++r) {
    int a = t + r * 256;
    if (a < kACOL) {
      float acc = ba[a];
      for (int c = 0; c < kDIM; ++c)
        acc = fmaf(feat[c], Wa[c * kACOL + a], acc);
      att[a] = acc * kSCALE;
    }
  }
  __syncthreads();

  if (t < 72) {
    float* gp = &att[t * 9];
    float m = gp[0];
#pragma unroll
    for (int q = 1; q < 9; ++q) m = fmaxf(m, gp[q]);
    float e[9], s = 0.f;
#pragma unroll
    for (int q = 0; q < 9; ++q) { e[q] = __expf(gp[q] - m); s += e[q]; }
    float inv = 1.f / s;
#pragma unroll
    for (int q = 0; q < 9; ++q) gp[q] = e[q] * inv;
  }
  __syncthreads();

  int n = t >> 5;
  const float* an = &att[n * 81];
#pragma unroll
  for (int p = 0; p < 9; ++p) {
    float acc = 0.f;
#pragma unroll
    for (int q = 0; q < 9; ++q)
      acc = fmaf(an[p * 9 + q], vu[q][t], acc);
    xw[(size_t)(l * 9 + p) * kDIM + t] = f2bf(acc);
  }
}

// ---------------------------------------------------------------------------
// fold (overlap-add gather) + projection @ Wp + bp. Output f32 HWC.
__global__ __launch_bounds__(256) void fold_proj(const bf16* __restrict__ xw,
                                                 const float* __restrict__ Wp,
                                                 const float* __restrict__ bp,
                                                 float* __restrict__ out_hwc) {
  __shared__ float folded[kDIM];
  int l = blockIdx.x;
  int Y = l / kHW, X = l % kHW;
  int t = threadIdx.x;

  float acc = 0.f;
#pragma unroll
  for (int i = 0; i < 3; ++i) {
    int ys = Y + 1 - i;
    if (ys < 0 || ys >= kHW) continue;
#pragma unroll
    for (int j = 0; j < 3; ++j) {
      int xs = X + 1 - j;
      if (xs < 0 || xs >= kHW) continue;
      int ls = ys * kHW + xs;
      int p = i * 3 + j;
      acc += bf2f(xw[(size_t)(ls * 9 + p) * kDIM + t]);
    }
  }
  folded[t] = acc;
  __syncthreads();

  float o = bp[t];
  for (int c = 0; c < kDIM; ++c)
    o = fmaf(folded[c], Wp[c * kDIM + t], o);
  out_hwc[l * kDIM + t] = o;
}

// ---------------------------------------------------------------------------
extern "C" void kernel_launch(void* const* d_in, const int* in_sizes, int n_in,
                              void* d_out, int out_size, void* d_ws, size_t ws_size,
                              hipStream_t stream) {
  const float* x   = (const float*)d_in[0];
  const float* fg  = (const float*)d_in[1];
  const float* bg  = (const float*)d_in[2];
  const float* Wc1 = (const float*)d_in[3];
  const float* s1  = (const float*)d_in[4];
  const float* b1  = (const float*)d_in[5];
  const float* Wc2 = (const float*)d_in[6];
  const float* s2  = (const float*)d_in[7];
  const float* b2  = (const float*)d_in[8];
  const float* Wv  = (const float*)d_in[9];
  const float* bv  = (const float*)d_in[10];
  const float* Wfg = (const float*)d_in[11];
  const float* bfg = (const float*)d_in[12];
  const float* Wbg = (const float*)d_in[13];
  const float* bbg = (const float*)d_in[14];
  const float* Wp  = (const float*)d_in[15];
  const float* bp  = (const float*)d_in[16];
  const float* Wc3 = (const float*)d_in[17];
  const float* s3  = (const float*)d_in[18];
  const float* b3  = (const float*)d_in[19];
  const float* Wc4 = (const float*)d_in[20];
  const float* s4  = (const float*)d_in[21];
  const float* b4  = (const float*)d_in[22];
  float* out = (float*)d_out;   // f32 NCHW

  float* ws = (float*)d_ws;
  float* A0 = ws;                          // fg/bg HWC f32       (409600)
  float* A2 = ws + 409600;                 // v HWC f32           (409600)
  float* A3 = ws + 819200;                 // x1 HWC f32          (409600)
  float* A1 = ws + 1228800;                // x2 HWC f32          (409600)
  bf16* XWb = (bf16*)(ws + 1638400);       // 3686400 bf16
  bf16* Wt1 = (bf16*)(ws + 3481600);       // 4 x 589824 bf16
  bf16* Wt2 = Wt1 + 589824;
  bf16* Wt3 = Wt2 + 589824;
  bf16* Wt4 = Wt3 + 589824;
  bf16* Pb0 = (bf16*)(ws + 4661248);       // padded HWC bf16 (451584)
  bf16* Pb1 = (bf16*)(ws + 4887040);       // padded HWC bf16 (451584)
  // total: 5112832 floats = 20.45 MB

  // zero padded-activation buffers (borders must be 0; interiors overwritten)
  hipMemsetAsync(Pb0, 0, (size_t)451584 * 2 * 2, stream);

  // weight transforms
  prep_w<<<2304, 256, 0, stream>>>(Wc1, Wt1);
  prep_w<<<2304, 256, 0, stream>>>(Wc2, Wt2);
  prep_w<<<2304, 256, 0, stream>>>(Wc3, Wt3);
  prep_w<<<2304, 256, 0, stream>>>(Wc4, Wt4);

  const dim3 convGrid(50, 8);

  // input_cbr
  prep_chw<<<kNPIX, 256, 0, stream>>>(x, Pb0);
  conv_mfma<<<convGrid, 256, 0, stream>>>(Pb0, Wt1, s1, b1, Pb1, nullptr);
  conv_mfma<<<convGrid, 256, 0, stream>>>(Pb1, Wt2, s2, b2, Pb0, nullptr);  // h0

  // v projection
  linear_v_pad<<<kNPIX, 256, 0, stream>>>(Pb0, Wv, bv, A2);

  // fg attention pass
  transpose_k<<<400, 256, 0, stream>>>(fg, A0, kDIM, kNPIX);
  attn_kernel<<<kNPIX, 256, 0, stream>>>(A0, A2, Wfg, bfg, XWb);
  fold_proj<<<kNPIX, 256, 0, stream>>>(XWb, Wp, bp, A3);           // x1 HWC

  // bg attention pass (v = x1)
  transpose_k<<<400, 256, 0, stream>>>(bg, A0, kDIM, kNPIX);
  attn_kernel<<<kNPIX, 256, 0, stream>>>(A0, A3, Wbg, bbg, XWb);
  fold_proj<<<kNPIX, 256, 0, stream>>>(XWb, Wp, bp, A1);           // x2 HWC

  // output_cbr (consumes HWC directly; no transpose needed)
  prep_hwc<<<kNPIX, 256, 0, stream>>>(A1, Pb1);
  conv_mfma<<<convGrid, 256, 0, stream>>>(Pb1, Wt3, s3, b3, Pb0, nullptr);
  conv_mfma<<<convGrid, 256, 0, stream>>>(Pb0, Wt4, s4, b4, nullptr, out);
}

// Round 4
// 178.381 us; speedup vs baseline: 4.4330x; 1.5006x over previous
//
#include <hip/hip_runtime.h>
#include <hip/hip_bf16.h>

namespace {
constexpr int kHW   = 40;
constexpr int kNPIX = kHW * kHW;        // 1600
constexpr int kDIM  = 256;
constexpr int kPADW = 42;
constexpr int kACOL = 648;              // heads * 9 * 9
constexpr float kSCALE = 0.17677669529663687f;  // 32^-0.5
}

using bf16 = __hip_bfloat16;
typedef __attribute__((ext_vector_type(8))) short sh8;    // 8 bf16 (A/B frag)
typedef __attribute__((ext_vector_type(4))) float f32x4;  // C/D frag

static __device__ __forceinline__ bf16 f2bf(float f)  { return __float2bfloat16(f); }
static __device__ __forceinline__ float bf2f(bf16 b)  { return __bfloat162float(b); }

// ---------------------------------------------------------------------------
// W[oc][ic][3][3] f32 -> Wt[t][oc][ic] bf16. Block per oc; LDS staged.
__global__ __launch_bounds__(256) void prep_w(const float* __restrict__ W,
                                              bf16* __restrict__ Wt) {
  __shared__ float lds[2304];
  int oc = blockIdx.x, t = threadIdx.x;
  const float* src = W + (size_t)oc * 2304;
  for (int i = t; i < 2304; i += 256) lds[i] = src[i];
  __syncthreads();
#pragma unroll
  for (int tap = 0; tap < 9; ++tap)
    Wt[(size_t)(tap * 256 + oc) * 256 + t] = f2bf(lds[t * 9 + tap]);
}

// Tiled transpose with bounds: in R x C f32 -> out C x R bf16.
__global__ __launch_bounds__(256) void transpose_to_bf16(const float* __restrict__ in,
                                                         bf16* __restrict__ out,
                                                         int R, int C) {
  __shared__ float tile[32][33];
  int nbx = (C + 31) / 32;
  int bx = blockIdx.x % nbx, by = blockIdx.x / nbx;
  int c0 = bx * 32, r0 = by * 32;
  int tx = threadIdx.x & 31, ty = threadIdx.x >> 5;
#pragma unroll
  for (int rr = ty; rr < 32; rr += 8) {
    int r = r0 + rr, c = c0 + tx;
    tile[rr][tx] = (r < R && c < C) ? in[(size_t)r * C + c] : 0.f;
  }
  __syncthreads();
#pragma unroll
  for (int rr = ty; rr < 32; rr += 8) {
    int c = c0 + rr, r = r0 + tx;
    if (c < C && r < R) out[(size_t)c * R + r] = f2bf(tile[tx][rr]);
  }
}

// CHW f32 -> padded HWC bf16 (interior only; borders pre-zeroed)
__global__ __launch_bounds__(256) void prep_chw(const float* __restrict__ in,
                                                bf16* __restrict__ outb) {
  int l = blockIdx.x, c = threadIdx.x;
  int y = l / kHW, x = l % kHW;
  outb[((y + 1) * kPADW + x + 1) * kDIM + c] = f2bf(in[c * kNPIX + l]);
}

// ---------------------------------------------------------------------------
// MFMA implicit-GEMM 3x3 conv + scale/shift + ReLU (as round 3, verified).
__global__ __launch_bounds__(256) void conv_mfma(const bf16* __restrict__ act,
                                                 const bf16* __restrict__ wt,
                                                 const float* __restrict__ sc,
                                                 const float* __restrict__ sh_,
                                                 bf16* __restrict__ outPad,
                                                 float* __restrict__ outF32) {
  int pt  = blockIdx.x;
  int oc0 = blockIdx.y * 32;
  int ty0 = (pt / 5) * 4;
  int tx0 = (pt % 5) * 8;
  int tid = threadIdx.x;
  int w = tid >> 6, lane = tid & 63, g = lane >> 4, r16 = lane & 15;

  int dy0 = r16 >> 3,       dx0 = r16 & 7;
  int dy1 = 2 + (r16 >> 3), dx1 = r16 & 7;

  f32x4 acc[2][2] = {};
  int icq = w * 64;

  for (int t = 0; t < 9; ++t) {
    int tyy = t / 3, txx = t % 3;
    const bf16* aBase0 = act + (size_t)((ty0 + dy0 + tyy) * kPADW + tx0 + dx0 + txx) * kDIM;
    const bf16* aBase1 = act + (size_t)((ty0 + dy1 + tyy) * kPADW + tx0 + dx1 + txx) * kDIM;
    const bf16* bBase  = wt + (size_t)(t * 256 + oc0 + r16) * 256;
#pragma unroll
    for (int kk = 0; kk < 2; ++kk) {
      int ic = icq + kk * 32 + g * 8;
      sh8 a0 = *(const sh8*)(aBase0 + ic);
      sh8 a1 = *(const sh8*)(aBase1 + ic);
      sh8 b0 = *(const sh8*)(bBase + ic);
      sh8 b1 = *(const sh8*)(bBase + 16 * 256 + ic);
      acc[0][0] = __builtin_amdgcn_mfma_f32_16x16x32_bf16(a0, b0, acc[0][0], 0, 0, 0);
      acc[0][1] = __builtin_amdgcn_mfma_f32_16x16x32_bf16(a0, b1, acc[0][1], 0, 0, 0);
      acc[1][0] = __builtin_amdgcn_mfma_f32_16x16x32_bf16(a1, b0, acc[1][0], 0, 0, 0);
      acc[1][1] = __builtin_amdgcn_mfma_f32_16x16x32_bf16(a1, b1, acc[1][1], 0, 0, 0);
    }
  }

  __shared__ float red[4][32][33];
#pragma unroll
  for (int mi = 0; mi < 2; ++mi)
#pragma unroll
    for (int ni = 0; ni < 2; ++ni)
#pragma unroll
      for (int q = 0; q < 4; ++q)
        red[w][mi * 16 + g * 4 + q][ni * 16 + r16] = acc[mi][ni][q];
  __syncthreads();

  int pixL = tid >> 3;
  int ocL  = (tid & 7) * 4;
  int dy = pixL >> 3, dx = pixL & 7;
  int oc = oc0 + ocL;
  int y = ty0 + dy, x = tx0 + dx;
  float v[4];
#pragma unroll
  for (int j = 0; j < 4; ++j) {
    float s = red[0][pixL][ocL + j] + red[1][pixL][ocL + j] +
              red[2][pixL][ocL + j] + red[3][pixL][ocL + j];
    v[j] = fmaxf(fmaf(s, sc[oc + j], sh_[oc + j]), 0.f);
  }
  if (outPad) {
    bf16 pk[4];
#pragma unroll
    for (int j = 0; j < 4; ++j) pk[j] = f2bf(v[j]);
    *reinterpret_cast<uint2*>(outPad + (size_t)((y + 1) * kPADW + x + 1) * kDIM + oc) =
        *reinterpret_cast<uint2*>(pk);
  } else {
#pragma unroll
    for (int j = 0; j < 4; ++j)
      outF32[(oc + j) * kNPIX + y * kHW + x] = v[j];
  }
}

// ---------------------------------------------------------------------------
// Generic MFMA GEMM: out[1600 x N] = A[1600 x 256] @ Bt^T (+bias).
// Bt is [N][256] (k-contiguous). Tile 32 pix x 32 col, 4 waves K-split.
// LOGITS: N=648, out = (acc+bias)*SCALE into Lg[l*648+col] (bounds-checked).
// else:   N=256, out = acc+bias -> f32 HWC (if outF32) / padded bf16 (if outPad).
template <bool PADDED_A, bool LOGITS>
__global__ __launch_bounds__(256) void gemm_mfma(const bf16* __restrict__ A,
                                                 const bf16* __restrict__ Bt,
                                                 const float* __restrict__ bias,
                                                 float* __restrict__ outF32,
                                                 bf16* __restrict__ outPad) {
  int l0   = blockIdx.x * 32;
  int col0 = blockIdx.y * 32;
  int tid = threadIdx.x;
  int w = tid >> 6, lane = tid & 63, g = lane >> 4, r16 = lane & 15;

  const bf16* aBase[2];
#pragma unroll
  for (int mi = 0; mi < 2; ++mi) {
    int l = l0 + mi * 16 + r16;
    if (PADDED_A) {
      int y = l / kHW, x = l % kHW;
      aBase[mi] = A + (size_t)((y + 1) * kPADW + x + 1) * kDIM;
    } else {
      aBase[mi] = A + (size_t)l * kDIM;
    }
  }
  const bf16* bBase0 = Bt + (size_t)(col0 + r16) * kDIM;
  const bf16* bBase1 = bBase0 + 16 * kDIM;

  f32x4 acc[2][2] = {};
  int icq = w * 64 + g * 8;
#pragma unroll
  for (int kk = 0; kk < 2; ++kk) {
    int ic = icq + kk * 32;
    sh8 a0 = *(const sh8*)(aBase[0] + ic);
    sh8 a1 = *(const sh8*)(aBase[1] + ic);
    sh8 b0 = *(const sh8*)(bBase0 + ic);
    sh8 b1 = *(const sh8*)(bBase1 + ic);
    acc[0][0] = __builtin_amdgcn_mfma_f32_16x16x32_bf16(a0, b0, acc[0][0], 0, 0, 0);
    acc[0][1] = __builtin_amdgcn_mfma_f32_16x16x32_bf16(a0, b1, acc[0][1], 0, 0, 0);
    acc[1][0] = __builtin_amdgcn_mfma_f32_16x16x32_bf16(a1, b0, acc[1][0], 0, 0, 0);
    acc[1][1] = __builtin_amdgcn_mfma_f32_16x16x32_bf16(a1, b1, acc[1][1], 0, 0, 0);
  }

  __shared__ float red[4][32][33];
#pragma unroll
  for (int mi = 0; mi < 2; ++mi)
#pragma unroll
    for (int ni = 0; ni < 2; ++ni)
#pragma unroll
      for (int q = 0; q < 4; ++q)
        red[w][mi * 16 + g * 4 + q][ni * 16 + r16] = acc[mi][ni][q];
  __syncthreads();

  int pixL = tid >> 3;
  int ocL  = (tid & 7) * 4;
  int l = l0 + pixL;
  int col = col0 + ocL;

  float s[4];
#pragma unroll
  for (int j = 0; j < 4; ++j)
    s[j] = red[0][pixL][ocL + j] + red[1][pixL][ocL + j] +
           red[2][pixL][ocL + j] + red[3][pixL][ocL + j];

  if (LOGITS) {
#pragma unroll
    for (int j = 0; j < 4; ++j)
      if (col + j < kACOL)
        outF32[(size_t)l * kACOL + col + j] = (s[j] + bias[col + j]) * kSCALE;
  } else {
    float v[4];
#pragma unroll
    for (int j = 0; j < 4; ++j) v[j] = s[j] + bias[col + j];
    if (outF32)
      *reinterpret_cast<float4*>(outF32 + (size_t)l * kDIM + col) =
          *reinterpret_cast<float4*>(v);
    if (outPad) {
      int y = l / kHW, x = l % kHW;
      bf16 pk[4];
#pragma unroll
      for (int j = 0; j < 4; ++j) pk[j] = f2bf(v[j]);
      *reinterpret_cast<uint2*>(outPad + (size_t)((y + 1) * kPADW + x + 1) * kDIM + col) =
          *reinterpret_cast<uint2*>(pk);
    }
  }
}

// ---------------------------------------------------------------------------
// softmax over q per (head,p) + PV. Reads logits Lg[l][648], v f32 HWC.
__global__ __launch_bounds__(256) void softmax_pv(const float* __restrict__ Lg,
                                                  const float* __restrict__ v_hwc,
                                                  bf16* __restrict__ xw) {
  __shared__ float att[kACOL];
  __shared__ float vu[9][kDIM];

  int l = blockIdx.x;
  int y = l / kHW, x = l % kHW;
  int t = threadIdx.x;

#pragma unroll
  for (int r = 0; r < 3; ++r) {
    int a = t + r * 256;
    if (a < kACOL) att[a] = Lg[(size_t)l * kACOL + a];
  }
#pragma unroll
  for (int q = 0; q < 9; ++q) {
    int qy = y + q / 3 - 1;
    int qx = x + q % 3 - 1;
    bool ok = (qy >= 0 && qy < kHW && qx >= 0 && qx < kHW);
    vu[q][t] = ok ? v_hwc[(size_t)(qy * kHW + qx) * kDIM + t] : 0.f;
  }
  __syncthreads();

  if (t < 72) {
    float* gp = &att[t * 9];
    float m = gp[0];
#pragma unroll
    for (int q = 1; q < 9; ++q) m = fmaxf(m, gp[q]);
    float e[9], sm = 0.f;
#pragma unroll
    for (int q = 0; q < 9; ++q) { e[q] = __expf(gp[q] - m); sm += e[q]; }
    float inv = 1.f / sm;
#pragma unroll
    for (int q = 0; q < 9; ++q) gp[q] = e[q] * inv;
  }
  __syncthreads();

  int n = t >> 5;
  const float* an = &att[n * 81];
#pragma unroll
  for (int p = 0; p < 9; ++p) {
    float acc = 0.f;
#pragma unroll
    for (int q = 0; q < 9; ++q)
      acc = fmaf(an[p * 9 + q], vu[q][t], acc);
    xw[(size_t)(l * 9 + p) * kDIM + t] = f2bf(acc);
  }
}

// ---------------------------------------------------------------------------
// fold: overlap-add gather of xw -> F[1600][256] bf16 (f32 accumulate).
__global__ __launch_bounds__(256) void fold_k(const bf16* __restrict__ xw,
                                              bf16* __restrict__ F) {
  int l = blockIdx.x;
  int Y = l / kHW, X = l % kHW;
  int t = threadIdx.x;
  float acc = 0.f;
#pragma unroll
  for (int i = 0; i < 3; ++i) {
    int ys = Y + 1 - i;
    if (ys < 0 || ys >= kHW) continue;
#pragma unroll
    for (int j = 0; j < 3; ++j) {
      int xs = X + 1 - j;
      if (xs < 0 || xs >= kHW) continue;
      acc += bf2f(xw[(size_t)((ys * kHW + xs) * 9 + i * 3 + j) * kDIM + t]);
    }
  }
  F[(size_t)l * kDIM + t] = f2bf(acc);
}

// ---------------------------------------------------------------------------
extern "C" void kernel_launch(void* const* d_in, const int* in_sizes, int n_in,
                              void* d_out, int out_size, void* d_ws, size_t ws_size,
                              hipStream_t stream) {
  const float* x   = (const float*)d_in[0];
  const float* fg  = (const float*)d_in[1];
  const float* bg  = (const float*)d_in[2];
  const float* Wc1 = (const float*)d_in[3];
  const float* s1  = (const float*)d_in[4];
  const float* b1  = (const float*)d_in[5];
  const float* Wc2 = (const float*)d_in[6];
  const float* s2  = (const float*)d_in[7];
  const float* b2  = (const float*)d_in[8];
  const float* Wv  = (const float*)d_in[9];
  const float* bv  = (const float*)d_in[10];
  const float* Wfg = (const float*)d_in[11];
  const float* bfg = (const float*)d_in[12];
  const float* Wbg = (const float*)d_in[13];
  const float* bbg = (const float*)d_in[14];
  const float* Wp  = (const float*)d_in[15];
  const float* bp  = (const float*)d_in[16];
  const float* Wc3 = (const float*)d_in[17];
  const float* s3  = (const float*)d_in[18];
  const float* b3  = (const float*)d_in[19];
  const float* Wc4 = (const float*)d_in[20];
  const float* s4  = (const float*)d_in[21];
  const float* b4  = (const float*)d_in[22];
  float* out = (float*)d_out;   // f32 NCHW

  float* ws = (float*)d_ws;
  float* A2   = ws;                         // v f32 HWC        (409600)
  float* A3   = ws + 409600;                // x1 f32 HWC       (409600)
  float* Lg   = ws + 819200;                // logits f32       (1036800)
  bf16* XWb   = (bf16*)(ws + 1856000);      // 3686400 bf16
  bf16* SH    = (bf16*)(ws + 3699200);      // feat/folded bf16 (409600)
  bf16* Wt1   = (bf16*)(ws + 3904000);      // 4 x 589824 bf16
  bf16* Wt2   = Wt1 + 589824;
  bf16* Wt3   = Wt2 + 589824;
  bf16* Wt4   = Wt3 + 589824;
  bf16* WaTf  = (bf16*)(ws + 5083648);      // 672x256 bf16
  bf16* WaTb  = (bf16*)(ws + 5169664);      // 672x256 bf16
  bf16* WvT   = (bf16*)(ws + 5255680);      // 256x256 bf16
  bf16* WpT   = (bf16*)(ws + 5288448);      // 256x256 bf16
  bf16* Pb0   = (bf16*)(ws + 5321216);      // padded HWC bf16 (451584)
  bf16* Pb1   = (bf16*)(ws + 5547008);      // padded HWC bf16 (451584)
  // end: 5772800 floats = 23.09 MB

  // zero both padded buffers (adjacent)
  hipMemsetAsync(Pb0, 0, (size_t)451584 * 2 * 2, stream);

  // weight preps
  prep_w<<<256, 256, 0, stream>>>(Wc1, Wt1);
  prep_w<<<256, 256, 0, stream>>>(Wc2, Wt2);
  prep_w<<<256, 256, 0, stream>>>(Wc3, Wt3);
  prep_w<<<256, 256, 0, stream>>>(Wc4, Wt4);
  transpose_to_bf16<<<21 * 8, 256, 0, stream>>>(Wfg, WaTf, 256, kACOL);
  transpose_to_bf16<<<21 * 8, 256, 0, stream>>>(Wbg, WaTb, 256, kACOL);
  transpose_to_bf16<<<64, 256, 0, stream>>>(Wv, WvT, 256, 256);
  transpose_to_bf16<<<64, 256, 0, stream>>>(Wp, WpT, 256, 256);

  const dim3 convGrid(50, 8);
  const dim3 gemmN256(50, 8);
  const dim3 gemmN648(50, 21);

  // input_cbr
  prep_chw<<<kNPIX, 256, 0, stream>>>(x, Pb0);
  conv_mfma<<<convGrid, 256, 0, stream>>>(Pb0, Wt1, s1, b1, Pb1, nullptr);
  conv_mfma<<<convGrid, 256, 0, stream>>>(Pb1, Wt2, s2, b2, Pb0, nullptr);  // h0

  // v = h0 @ Wv + bv
  gemm_mfma<true, false><<<gemmN256, 256, 0, stream>>>(Pb0, WvT, bv, A2, nullptr);

  // fg attention pass
  transpose_to_bf16<<<50 * 8, 256, 0, stream>>>(fg, SH, 256, kNPIX);
  gemm_mfma<false, true><<<gemmN648, 256, 0, stream>>>(SH, WaTf, bfg, Lg, nullptr);
  softmax_pv<<<kNPIX, 256, 0, stream>>>(Lg, A2, XWb);
  fold_k<<<kNPIX, 256, 0, stream>>>(XWb, SH);
  gemm_mfma<false, false><<<gemmN256, 256, 0, stream>>>(SH, WpT, bp, A3, nullptr); // x1

  // bg attention pass (v = x1)
  transpose_to_bf16<<<50 * 8, 256, 0, stream>>>(bg, SH, 256, kNPIX);
  gemm_mfma<false, true><<<gemmN648, 256, 0, stream>>>(SH, WaTb, bbg, Lg, nullptr);
  softmax_pv<<<kNPIX, 256, 0, stream>>>(Lg, A3, XWb);
  fold_k<<<kNPIX, 256, 0, stream>>>(XWb, SH);
  gemm_mfma<false, false><<<gemmN256, 256, 0, stream>>>(SH, WpT, bp, nullptr, Pb1); // x2 padded

  // output_cbr
  conv_mfma<<<convGrid, 256, 0, stream>>>(Pb1, Wt3, s3, b3, Pb0, nullptr);
  conv_mfma<<<convGrid, 256, 0, stream>>>(Pb0, Wt4, s4, b4, nullptr, out);
}

// Round 5
// 139.085 us; speedup vs baseline: 5.6854x; 1.2825x over previous
//
#include <hip/hip_runtime.h>
#include <hip/hip_bf16.h>

namespace {
constexpr int kHW   = 40;
constexpr int kNPIX = kHW * kHW;        // 1600
constexpr int kDIM  = 256;
constexpr int kPADW = 42;
constexpr int kACOL = 648;              // heads * 9 * 9
constexpr float kSCALE = 0.17677669529663687f;  // 32^-0.5
}

using bf16 = __hip_bfloat16;
typedef __attribute__((ext_vector_type(8))) short sh8;    // 8 bf16 (A/B frag)
typedef __attribute__((ext_vector_type(4))) float f32x4;  // C/D frag

static __device__ __forceinline__ bf16 f2bf(float f)  { return __float2bfloat16(f); }
static __device__ __forceinline__ float bf2f(bf16 b)  { return __bfloat162float(b); }

// ---------------------------------------------------------------------------
// ONE fused prep kernel (segmented grid, block-uniform branches):
//  [0,1024)     : 4 conv weights  W[oc][ic][3][3] f32 -> Wt[tap][oc][ic] bf16
//  [1024,1360)  : Wfg/Wbg [256][648] f32 -> [672][256] bf16 (cols>=648 zeroed)
//  [1360,1488)  : Wv/Wp   [256][256] f32 -> transposed bf16
//  [1488,2288)  : fg/bg CHW f32 -> HWC bf16 [1600][256]
//  [2288,2688)  : x CHW f32 -> padded HWC bf16 interior
//  [2688,2852)  : zero borders of Pb0/Pb1
__global__ __launch_bounds__(256) void prep_all(
    const float* __restrict__ Wc1, const float* __restrict__ Wc2,
    const float* __restrict__ Wc3, const float* __restrict__ Wc4,
    const float* __restrict__ Wfg, const float* __restrict__ Wbg,
    const float* __restrict__ Wv,  const float* __restrict__ Wp,
    const float* __restrict__ x,   const float* __restrict__ fg,
    const float* __restrict__ bg,
    bf16* __restrict__ Wt1, bf16* __restrict__ Wt2,
    bf16* __restrict__ Wt3, bf16* __restrict__ Wt4,
    bf16* __restrict__ WaTf, bf16* __restrict__ WaTb,
    bf16* __restrict__ WvT, bf16* __restrict__ WpT,
    bf16* __restrict__ SHf, bf16* __restrict__ SHb,
    bf16* __restrict__ Pb0, bf16* __restrict__ Pb1) {
  __shared__ float smem[2304];
  int b = blockIdx.x, t = threadIdx.x;

  if (b < 1024) {                       // conv weight transform
    int w = b >> 8, oc = b & 255;
    const float* src = (w == 0) ? Wc1 : (w == 1) ? Wc2 : (w == 2) ? Wc3 : Wc4;
    bf16* dst        = (w == 0) ? Wt1 : (w == 1) ? Wt2 : (w == 2) ? Wt3 : Wt4;
    src += (size_t)oc * 2304;
    for (int i = t; i < 2304; i += 256) smem[i] = src[i];
    __syncthreads();
#pragma unroll
    for (int tap = 0; tap < 9; ++tap)
      dst[(size_t)(tap * 256 + oc) * 256 + t] = f2bf(smem[t * 9 + tap]);
    return;
  }

  float (*tile)[33] = (float(*)[33])smem;
  int tx = t & 31, ty = t >> 5;

  if (b < 1360) {                       // Wa transposes (R=256, C=648 -> 672x256)
    int b2 = b - 1024;
    const float* in = (b2 < 168) ? Wfg : Wbg;
    bf16* outp      = (b2 < 168) ? WaTf : WaTb;
    int rb = b2 % 168;
    int bx = rb % 21, by = rb / 21;
    int c0 = bx * 32, r0 = by * 32;
#pragma unroll
    for (int rr = ty; rr < 32; rr += 8) {
      int c = c0 + tx;
      tile[rr][tx] = (c < kACOL) ? in[(size_t)(r0 + rr) * kACOL + c] : 0.f;
    }
    __syncthreads();
#pragma unroll
    for (int rr = ty; rr < 32; rr += 8)
      outp[(size_t)(c0 + rr) * 256 + r0 + tx] = f2bf(tile[tx][rr]);
    return;
  }

  if (b < 1488) {                       // Wv / Wp transpose (256x256)
    int b3 = b - 1360;
    const float* in = (b3 < 64) ? Wv : Wp;
    bf16* outp      = (b3 < 64) ? WvT : WpT;
    int rb = b3 & 63;
    int bx = rb & 7, by = rb >> 3;
    int c0 = bx * 32, r0 = by * 32;
#pragma unroll
    for (int rr = ty; rr < 32; rr += 8)
      tile[rr][tx] = in[(size_t)(r0 + rr) * 256 + c0 + tx];
    __syncthreads();
#pragma unroll
    for (int rr = ty; rr < 32; rr += 8)
      outp[(size_t)(c0 + rr) * 256 + r0 + tx] = f2bf(tile[tx][rr]);
    return;
  }

  if (b < 2288) {                       // fg/bg CHW -> HWC bf16
    int b4 = b - 1488;
    const float* in = (b4 < 400) ? fg : bg;
    bf16* outp      = (b4 < 400) ? SHf : SHb;
    int rb = b4 % 400;
    int bx = rb % 50, by = rb / 50;
    int c0 = bx * 32, r0 = by * 32;
#pragma unroll
    for (int rr = ty; rr < 32; rr += 8)
      tile[rr][tx] = in[(size_t)(r0 + rr) * kNPIX + c0 + tx];
    __syncthreads();
#pragma unroll
    for (int rr = ty; rr < 32; rr += 8)
      outp[(size_t)(c0 + rr) * 256 + r0 + tx] = f2bf(tile[tx][rr]);
    return;
  }

  if (b < 2688) {                       // x CHW -> padded HWC bf16 interior
    int b5 = b - 2288;
    int bx = b5 % 50, by = b5 / 50;
    int c0 = bx * 32, r0 = by * 32;
#pragma unroll
    for (int rr = ty; rr < 32; rr += 8)
      tile[rr][tx] = x[(size_t)(r0 + rr) * kNPIX + c0 + tx];
    __syncthreads();
#pragma unroll
    for (int rr = ty; rr < 32; rr += 8) {
      int l = c0 + rr;
      int yy = l / kHW, xx = l % kHW;
      Pb0[(size_t)((yy + 1) * kPADW + xx + 1) * kDIM + r0 + tx] = f2bf(tile[tx][rr]);
    }
    return;
  }

  {                                     // zero pad borders of Pb0 & Pb1
    int k = b - 2688;                   // 0..163
    int py, px;
    if (k < 42)      { py = 0;         px = k; }
    else if (k < 84) { py = 41;        px = k - 42; }
    else if (k < 124){ py = k - 84 + 1; px = 0; }
    else             { py = k - 124 + 1; px = 41; }
    size_t off = (size_t)(py * kPADW + px) * kDIM + t;
    Pb0[off] = f2bf(0.f);
    Pb1[off] = f2bf(0.f);
  }
}

// ---------------------------------------------------------------------------
// MFMA implicit-GEMM 3x3 conv + scale/shift + ReLU (verified structure).
__global__ __launch_bounds__(256) void conv_mfma(const bf16* __restrict__ act,
                                                 const bf16* __restrict__ wt,
                                                 const float* __restrict__ sc,
                                                 const float* __restrict__ sh_,
                                                 bf16* __restrict__ outPad,
                                                 float* __restrict__ outF32) {
  int pt  = blockIdx.x;
  int oc0 = blockIdx.y * 32;
  int ty0 = (pt / 5) * 4;
  int tx0 = (pt % 5) * 8;
  int tid = threadIdx.x;
  int w = tid >> 6, lane = tid & 63, g = lane >> 4, r16 = lane & 15;

  int dy0 = r16 >> 3,       dx0 = r16 & 7;
  int dy1 = 2 + (r16 >> 3), dx1 = r16 & 7;

  f32x4 acc[2][2] = {};
  int icq = w * 64;

#pragma unroll
  for (int t = 0; t < 9; ++t) {
    int tyy = t / 3, txx = t % 3;
    const bf16* aBase0 = act + (size_t)((ty0 + dy0 + tyy) * kPADW + tx0 + dx0 + txx) * kDIM;
    const bf16* aBase1 = act + (size_t)((ty0 + dy1 + tyy) * kPADW + tx0 + dx1 + txx) * kDIM;
    const bf16* bBase  = wt + (size_t)(t * 256 + oc0 + r16) * 256;
#pragma unroll
    for (int kk = 0; kk < 2; ++kk) {
      int ic = icq + kk * 32 + g * 8;
      sh8 a0 = *(const sh8*)(aBase0 + ic);
      sh8 a1 = *(const sh8*)(aBase1 + ic);
      sh8 b0 = *(const sh8*)(bBase + ic);
      sh8 b1 = *(const sh8*)(bBase + 16 * 256 + ic);
      acc[0][0] = __builtin_amdgcn_mfma_f32_16x16x32_bf16(a0, b0, acc[0][0], 0, 0, 0);
      acc[0][1] = __builtin_amdgcn_mfma_f32_16x16x32_bf16(a0, b1, acc[0][1], 0, 0, 0);
      acc[1][0] = __builtin_amdgcn_mfma_f32_16x16x32_bf16(a1, b0, acc[1][0], 0, 0, 0);
      acc[1][1] = __builtin_amdgcn_mfma_f32_16x16x32_bf16(a1, b1, acc[1][1], 0, 0, 0);
    }
  }

  __shared__ float red[4][32][33];
#pragma unroll
  for (int mi = 0; mi < 2; ++mi)
#pragma unroll
    for (int ni = 0; ni < 2; ++ni)
#pragma unroll
      for (int q = 0; q < 4; ++q)
        red[w][mi * 16 + g * 4 + q][ni * 16 + r16] = acc[mi][ni][q];
  __syncthreads();

  int pixL = tid >> 3;
  int ocL  = (tid & 7) * 4;
  int dy = pixL >> 3, dx = pixL & 7;
  int oc = oc0 + ocL;
  int y = ty0 + dy, x = tx0 + dx;
  float v[4];
#pragma unroll
  for (int j = 0; j < 4; ++j) {
    float s = red[0][pixL][ocL + j] + red[1][pixL][ocL + j] +
              red[2][pixL][ocL + j] + red[3][pixL][ocL + j];
    v[j] = fmaxf(fmaf(s, sc[oc + j], sh_[oc + j]), 0.f);
  }
  if (outPad) {
    bf16 pk[4];
#pragma unroll
    for (int j = 0; j < 4; ++j) pk[j] = f2bf(v[j]);
    *reinterpret_cast<uint2*>(outPad + (size_t)((y + 1) * kPADW + x + 1) * kDIM + oc) =
        *reinterpret_cast<uint2*>(pk);
  } else {
#pragma unroll
    for (int j = 0; j < 4; ++j)
      outF32[(oc + j) * kNPIX + y * kHW + x] = v[j];
  }
}

// ---------------------------------------------------------------------------
// Generic MFMA GEMM: out[1600 x N] = A[1600 x 256] @ Bt^T (+bias).
// MODE 0: logits, N=648, f32 out (scaled);  MODE 1: bf16 flat HWC;
// MODE 2: bf16 padded HWC.
template <bool PADDED_A, int MODE>
__global__ __launch_bounds__(256) void gemm_mfma(const bf16* __restrict__ A,
                                                 const bf16* __restrict__ Bt,
                                                 const float* __restrict__ bias,
                                                 float* __restrict__ oF32,
                                                 bf16* __restrict__ oBf) {
  int l0   = blockIdx.x * 32;
  int col0 = blockIdx.y * 32;
  int tid = threadIdx.x;
  int w = tid >> 6, lane = tid & 63, g = lane >> 4, r16 = lane & 15;

  const bf16* aBase[2];
#pragma unroll
  for (int mi = 0; mi < 2; ++mi) {
    int l = l0 + mi * 16 + r16;
    if (PADDED_A) {
      int y = l / kHW, x = l % kHW;
      aBase[mi] = A + (size_t)((y + 1) * kPADW + x + 1) * kDIM;
    } else {
      aBase[mi] = A + (size_t)l * kDIM;
    }
  }
  const bf16* bBase0 = Bt + (size_t)(col0 + r16) * kDIM;
  const bf16* bBase1 = bBase0 + 16 * kDIM;

  f32x4 acc[2][2] = {};
  int icq = w * 64 + g * 8;
#pragma unroll
  for (int kk = 0; kk < 2; ++kk) {
    int ic = icq + kk * 32;
    sh8 a0 = *(const sh8*)(aBase[0] + ic);
    sh8 a1 = *(const sh8*)(aBase[1] + ic);
    sh8 b0 = *(const sh8*)(bBase0 + ic);
    sh8 b1 = *(const sh8*)(bBase1 + ic);
    acc[0][0] = __builtin_amdgcn_mfma_f32_16x16x32_bf16(a0, b0, acc[0][0], 0, 0, 0);
    acc[0][1] = __builtin_amdgcn_mfma_f32_16x16x32_bf16(a0, b1, acc[0][1], 0, 0, 0);
    acc[1][0] = __builtin_amdgcn_mfma_f32_16x16x32_bf16(a1, b0, acc[1][0], 0, 0, 0);
    acc[1][1] = __builtin_amdgcn_mfma_f32_16x16x32_bf16(a1, b1, acc[1][1], 0, 0, 0);
  }

  __shared__ float red[4][32][33];
#pragma unroll
  for (int mi = 0; mi < 2; ++mi)
#pragma unroll
    for (int ni = 0; ni < 2; ++ni)
#pragma unroll
      for (int q = 0; q < 4; ++q)
        red[w][mi * 16 + g * 4 + q][ni * 16 + r16] = acc[mi][ni][q];
  __syncthreads();

  int pixL = tid >> 3;
  int ocL  = (tid & 7) * 4;
  int l = l0 + pixL;
  int col = col0 + ocL;

  float s[4];
#pragma unroll
  for (int j = 0; j < 4; ++j)
    s[j] = red[0][pixL][ocL + j] + red[1][pixL][ocL + j] +
           red[2][pixL][ocL + j] + red[3][pixL][ocL + j];

  if (MODE == 0) {
#pragma unroll
    for (int j = 0; j < 4; ++j)
      if (col + j < kACOL)
        oF32[(size_t)l * kACOL + col + j] = (s[j] + bias[col + j]) * kSCALE;
  } else {
    bf16 pk[4];
#pragma unroll
    for (int j = 0; j < 4; ++j) pk[j] = f2bf(s[j] + bias[col + j]);
    if (MODE == 1) {
      *reinterpret_cast<uint2*>(oBf + (size_t)l * kDIM + col) =
          *reinterpret_cast<uint2*>(pk);
    } else {
      int y = l / kHW, x = l % kHW;
      *reinterpret_cast<uint2*>(oBf + (size_t)((y + 1) * kPADW + x + 1) * kDIM + col) =
          *reinterpret_cast<uint2*>(pk);
    }
  }
}

// ---------------------------------------------------------------------------
// softmax over q per (head,p) + PV. Logits f32 [l][648]; v bf16 HWC.
__global__ __launch_bounds__(256) void softmax_pv(const float* __restrict__ Lg,
                                                  const bf16* __restrict__ v_hwc,
                                                  bf16* __restrict__ xw) {
  __shared__ float att[kACOL];
  __shared__ float vu[9][kDIM];

  int l = blockIdx.x;
  int y = l / kHW, x = l % kHW;
  int t = threadIdx.x;

#pragma unroll
  for (int r = 0; r < 3; ++r) {
    int a = t + r * 256;
    if (a < kACOL) att[a] = Lg[(size_t)l * kACOL + a];
  }
#pragma unroll
  for (int q = 0; q < 9; ++q) {
    int qy = y + q / 3 - 1;
    int qx = x + q % 3 - 1;
    bool ok = (qy >= 0 && qy < kHW && qx >= 0 && qx < kHW);
    vu[q][t] = ok ? bf2f(v_hwc[(size_t)(qy * kHW + qx) * kDIM + t]) : 0.f;
  }
  __syncthreads();

  if (t < 72) {
    float* gp = &att[t * 9];
    float m = gp[0];
#pragma unroll
    for (int q = 1; q < 9; ++q) m = fmaxf(m, gp[q]);
    float e[9], sm = 0.f;
#pragma unroll
    for (int q = 0; q < 9; ++q) { e[q] = __expf(gp[q] - m); sm += e[q]; }
    float inv = 1.f / sm;
#pragma unroll
    for (int q = 0; q < 9; ++q) gp[q] = e[q] * inv;
  }
  __syncthreads();

  int n = t >> 5;
  const float* an = &att[n * 81];
#pragma unroll
  for (int p = 0; p < 9; ++p) {
    float acc = 0.f;
#pragma unroll
    for (int q = 0; q < 9; ++q)
      acc = fmaf(an[p * 9 + q], vu[q][t], acc);
    xw[(size_t)(l * 9 + p) * kDIM + t] = f2bf(acc);
  }
}

// ---------------------------------------------------------------------------
// fold: overlap-add gather of xw -> F[1600][256] bf16 (f32 accumulate).
__global__ __launch_bounds__(256) void fold_k(const bf16* __restrict__ xw,
                                              bf16* __restrict__ F) {
  int l = blockIdx.x;
  int Y = l / kHW, X = l % kHW;
  int t = threadIdx.x;
  float acc = 0.f;
#pragma unroll
  for (int i = 0; i < 3; ++i) {
    int ys = Y + 1 - i;
    if (ys < 0 || ys >= kHW) continue;
#pragma unroll
    for (int j = 0; j < 3; ++j) {
      int xs = X + 1 - j;
      if (xs < 0 || xs >= kHW) continue;
      acc += bf2f(xw[(size_t)((ys * kHW + xs) * 9 + i * 3 + j) * kDIM + t]);
    }
  }
  F[(size_t)l * kDIM + t] = f2bf(acc);
}

// ---------------------------------------------------------------------------
extern "C" void kernel_launch(void* const* d_in, const int* in_sizes, int n_in,
                              void* d_out, int out_size, void* d_ws, size_t ws_size,
                              hipStream_t stream) {
  const float* x   = (const float*)d_in[0];
  const float* fg  = (const float*)d_in[1];
  const float* bg  = (const float*)d_in[2];
  const float* Wc1 = (const float*)d_in[3];
  const float* s1  = (const float*)d_in[4];
  const float* b1  = (const float*)d_in[5];
  const float* Wc2 = (const float*)d_in[6];
  const float* s2  = (const float*)d_in[7];
  const float* b2  = (const float*)d_in[8];
  const float* Wv  = (const float*)d_in[9];
  const float* bv  = (const float*)d_in[10];
  const float* Wfg = (const float*)d_in[11];
  const float* bfg = (const float*)d_in[12];
  const float* Wbg = (const float*)d_in[13];
  const float* bbg = (const float*)d_in[14];
  const float* Wp  = (const float*)d_in[15];
  const float* bp  = (const float*)d_in[16];
  const float* Wc3 = (const float*)d_in[17];
  const float* s3  = (const float*)d_in[18];
  const float* b3  = (const float*)d_in[19];
  const float* Wc4 = (const float*)d_in[20];
  const float* s4  = (const float*)d_in[21];
  const float* b4  = (const float*)d_in[22];
  float* out = (float*)d_out;   // f32 NCHW

  float* ws = (float*)d_ws;
  float* Lg   = ws;                         // 1600x648 f32   (1036800)
  bf16* XWb   = (bf16*)(ws + 1036800);      // 3686400 bf16   (1843200 w)
  bf16* SHf   = (bf16*)(ws + 2880000);      // 409600 bf16    (204800 w)
  bf16* SHb   = (bf16*)(ws + 3084800);      // 409600 bf16
  bf16* FD    = (bf16*)(ws + 3289600);      // folded bf16
  bf16* Vb    = (bf16*)(ws + 3494400);      // v bf16 HWC
  bf16* X1b   = (bf16*)(ws + 3699200);      // x1 bf16 HWC
  bf16* Wt1   = (bf16*)(ws + 3904000);      // 4 x 589824 bf16
  bf16* Wt2   = Wt1 + 589824;
  bf16* Wt3   = Wt2 + 589824;
  bf16* Wt4   = Wt3 + 589824;
  bf16* WaTf  = (bf16*)(ws + 5083648);      // 672x256 bf16
  bf16* WaTb  = (bf16*)(ws + 5169664);
  bf16* WvT   = (bf16*)(ws + 5255680);      // 256x256 bf16
  bf16* WpT   = (bf16*)(ws + 5288448);
  bf16* Pb0   = (bf16*)(ws + 5321216);      // padded HWC bf16 (451584)
  bf16* Pb1   = (bf16*)(ws + 5547008);
  // end: 5772800 words = 23.09 MB

  // one fused prep dispatch (weights, transposes, padding, borders)
  prep_all<<<2852, 256, 0, stream>>>(Wc1, Wc2, Wc3, Wc4, Wfg, Wbg, Wv, Wp,
                                     x, fg, bg,
                                     Wt1, Wt2, Wt3, Wt4, WaTf, WaTb, WvT, WpT,
                                     SHf, SHb, Pb0, Pb1);

  const dim3 convGrid(50, 8);
  const dim3 gemmN256(50, 8);
  const dim3 gemmN648(50, 21);

  // input_cbr
  conv_mfma<<<convGrid, 256, 0, stream>>>(Pb0, Wt1, s1, b1, Pb1, nullptr);
  conv_mfma<<<convGrid, 256, 0, stream>>>(Pb1, Wt2, s2, b2, Pb0, nullptr);  // h0

  // v = h0 @ Wv + bv  (bf16 HWC)
  gemm_mfma<true, 1><<<gemmN256, 256, 0, stream>>>(Pb0, WvT, bv, nullptr, Vb);

  // fg attention pass
  gemm_mfma<false, 0><<<gemmN648, 256, 0, stream>>>(SHf, WaTf, bfg, Lg, nullptr);
  softmax_pv<<<kNPIX, 256, 0, stream>>>(Lg, Vb, XWb);
  fold_k<<<kNPIX, 256, 0, stream>>>(XWb, FD);
  gemm_mfma<false, 1><<<gemmN256, 256, 0, stream>>>(FD, WpT, bp, nullptr, X1b); // x1

  // bg attention pass (v = x1)
  gemm_mfma<false, 0><<<gemmN648, 256, 0, stream>>>(SHb, WaTb, bbg, Lg, nullptr);
  softmax_pv<<<kNPIX, 256, 0, stream>>>(Lg, X1b, XWb);
  fold_k<<<kNPIX, 256, 0, stream>>>(XWb, FD);
  gemm_mfma<false, 2><<<gemmN256, 256, 0, stream>>>(FD, WpT, bp, nullptr, Pb1); // x2 padded

  // output_cbr
  conv_mfma<<<convGrid, 256, 0, stream>>>(Pb1, Wt3, s3, b3, Pb0, nullptr);
  conv_mfma<<<convGrid, 256, 0, stream>>>(Pb0, Wt4, s4, b4, nullptr, out);
}